// Round 2
// baseline (174.825 us; speedup 1.0000x reference)
//
#include <hip/hip_runtime.h>
#include <math.h>

#define BB 256
#define TT 512
#define KK 20
#define START_TAG 18
#define STOP_TAG 19
#define NST 400  // KK*KK

__device__ __forceinline__ float fexp2(float x) {
    float r; asm("v_exp_f32 %0, %1" : "=v"(r) : "v"(x)); return r;
}
__device__ __forceinline__ float flog2(float x) {
    float r; asm("v_log_f32 %0, %1" : "=v"(r) : "v"(x)); return r;
}
__device__ __forceinline__ float frcp(float x) {
    float r; asm("v_rcp_f32 %0, %1" : "=v"(r) : "v"(x)); return r;
}
__device__ __forceinline__ float shflF(float v, int src) { return __shfl(v, src, 64); }

// Forward algorithm in LINEAR domain, one block (1 wave) per batch element.
// 3 lane-groups of 20: group g owns tag-chunk j in [8g, 8g+8) (g=2: 4 real + 4 zero).
// Lane (g,i) keeps e_ij for its chunk (prefetched+exp'd 8 deep) and W_j for its chunk.
// Per step: partial dot -> 2-rotation cross-group sum -> s_i on every lane ->
// bpermute-redistribute W chunk. Renormalize (rcp + log2 into OFF) every 4th step.
__global__ __launch_bounds__(64, 1) void fwd_kernel(
    const float* __restrict__ feats, const float* __restrict__ trans,
    const int* __restrict__ targets, const int* __restrict__ lengths,
    float* __restrict__ partialA)
{
    constexpr float LOG2E = 1.4426950408889634f;
    constexpr float LN2   = 0.6931471805599453f;

    const int b    = blockIdx.x;
    const int lane = threadIdx.x;
    const int len  = lengths[b];
    const float* fb = feats + (size_t)b * TT * NST;

    int g = lane / 20;
    int i = lane - 20 * g;
    if (g > 2) { g = 2; i = 19; }          // lanes 60-63: harmless duplicates, never sourced
    const int  off4 = i * 20 + 8 * g;      // float offset of this lane's chunk in a t-row
    const bool ghi  = (g < 2);             // whether hi half (4 floats) is real

    const int src1 = (lane + 20) % 60;     // rotate by 20 within the 60-lane ring
    const int src2 = (lane + 40) % 60;
    const int wj0  = 8 * g;                // W-redistribute sources: lanes wj0..wj0+7

    // ---- init: alpha2_i(0) = f[b,0,i,START]*log2e ; W_j = 2^(alpha2_j - c0), OFF = c0
    float a2own = fb[i * KK + START_TAG] * LOG2E;
    float c0  = shflF(a2own, 0);
    float OFF = c0;
    float s   = fexp2(a2own - c0);         // own-tag linear weight (epilogue state)
    float W0 = shflF(s, wj0 + 0), W1 = shflF(s, wj0 + 1);
    float W2 = shflF(s, wj0 + 2), W3 = shflF(s, wj0 + 3);
    float W4 = shflF(s, wj0 + 4), W5 = shflF(s, wj0 + 5);
    float W6 = shflF(s, wj0 + 6), W7 = shflF(s, wj0 + 7);

    struct EB { float4 lo, hi; };

    auto LOAD = [&](EB& d, int t) {
        int tc = (t < len) ? t : (len - 1);            // clamp: redundant but in-bounds
        const float4* p = (const float4*)(fb + (size_t)tc * NST + off4);
        float4 lo = p[0];
        float4 hi = make_float4(0.f, 0.f, 0.f, 0.f);
        if (ghi) hi = p[1];
        d.lo.x = fexp2(lo.x * LOG2E);
        d.lo.y = fexp2(lo.y * LOG2E);
        d.lo.z = fexp2(lo.z * LOG2E);
        d.lo.w = fexp2(lo.w * LOG2E);
        float ex0 = fexp2(hi.x * LOG2E);
        float ex1 = fexp2(hi.y * LOG2E);
        float ex2 = fexp2(hi.z * LOG2E);
        float ex3 = fexp2(hi.w * LOG2E);
        d.hi.x = ghi ? ex0 : 0.f;
        d.hi.y = ghi ? ex1 : 0.f;
        d.hi.z = ghi ? ex2 : 0.f;
        d.hi.w = ghi ? ex3 : 0.f;
    };

    auto STEP = [&](const EB& E, bool renorm) {
        float pa = E.lo.x * W0;
        float pb = E.lo.y * W1;
        pa = fmaf(E.lo.z, W2, pa);
        pb = fmaf(E.lo.w, W3, pb);
        pa = fmaf(E.hi.x, W4, pa);
        pb = fmaf(E.hi.y, W5, pb);
        pa = fmaf(E.hi.z, W6, pa);
        pb = fmaf(E.hi.w, W7, pb);
        float pt = pa + pb;
        float r1 = shflF(pt, src1);
        float r2 = shflF(pt, src2);
        s = pt + r1 + r2;                  // s_i, identical on the 3 group copies
        W0 = shflF(s, wj0 + 0); W1 = shflF(s, wj0 + 1);
        W2 = shflF(s, wj0 + 2); W3 = shflF(s, wj0 + 3);
        W4 = shflF(s, wj0 + 4); W5 = shflF(s, wj0 + 5);
        W6 = shflF(s, wj0 + 6); W7 = shflF(s, wj0 + 7);
        if (renorm) {
            float b0v  = shflF(s, 0);
            float rinv = frcp(b0v);
            W0 *= rinv; W1 *= rinv; W2 *= rinv; W3 *= rinv;
            W4 *= rinv; W5 *= rinv; W6 *= rinv; W7 *= rinv;
            OFF += flog2(b0v);
        }
    };

    EB e0, e1, e2, e3, e4, e5, e6, e7;
    LOAD(e0, 1); LOAD(e1, 2); LOAD(e2, 3); LOAD(e3, 4);
    LOAD(e4, 5); LOAD(e5, 6); LOAD(e6, 7); LOAD(e7, 8);

    int t = 1;
    while (t < len) {
        STEP(e0, false); LOAD(e0, t + 8); if (++t >= len) break;
        STEP(e1, false); LOAD(e1, t + 8); if (++t >= len) break;
        STEP(e2, false); LOAD(e2, t + 8); if (++t >= len) break;
        STEP(e3, true ); LOAD(e3, t + 8); if (++t >= len) break;
        STEP(e4, false); LOAD(e4, t + 8); if (++t >= len) break;
        STEP(e5, false); LOAD(e5, t + 8); if (++t >= len) break;
        STEP(e6, false); LOAD(e6, t + 8); if (++t >= len) break;
        STEP(e7, true ); LOAD(e7, t + 8); ++t;
    }

    // ---- epilogue: LSE_i(alpha_i + trans[STOP,i]) in nats, minus trans[STOP,last_tag]
    float tr = trans[STOP_TAG * KK + i];
    float z = (lane < KK) ? s * fexp2(tr * LOG2E) : 0.f;
    #pragma unroll
    for (int o = 32; o > 0; o >>= 1) z += __shfl_xor(z, o, 64);
    if (lane == 0) {
        float lse = LN2 * (OFF + flog2(z));
        int last_tag = targets[b * TT + (len - 1)];
        partialA[b] = lse - trans[STOP_TAG * KK + last_tag];
    }
}

// Gold path score gather: one thread per (b, t)
__global__ __launch_bounds__(256) void gold_kernel(
    const float* __restrict__ feats, const int* __restrict__ targets,
    const int* __restrict__ lengths, float* __restrict__ partialG)
{
    const int b   = blockIdx.x;
    const int tt  = blockIdx.y * 256 + threadIdx.x;
    const int len = lengths[b];

    float val = 0.f;
    if (tt < len) {
        int tgt  = targets[b * TT + tt];
        int prev = (tt > 0) ? targets[b * TT + tt - 1] : START_TAG;
        val = feats[((size_t)b * TT + tt) * NST + tgt * KK + prev];
    }
    #pragma unroll
    for (int off = 32; off > 0; off >>= 1) val += __shfl_down(val, off);

    __shared__ float wsum[4];
    if ((threadIdx.x & 63) == 0) wsum[threadIdx.x >> 6] = val;
    __syncthreads();
    if (threadIdx.x == 0)
        partialG[b * gridDim.y + blockIdx.y] = wsum[0] + wsum[1] + wsum[2] + wsum[3];
}

// out = sum(partialA) - sum(partialG); deterministic single-block reduce
__global__ __launch_bounds__(256) void final_kernel(
    const float* __restrict__ partialA, const float* __restrict__ partialG,
    float* __restrict__ out)
{
    int tid = threadIdx.x;
    float v = partialA[tid] - partialG[tid] - partialG[tid + 256];
    #pragma unroll
    for (int off = 32; off > 0; off >>= 1) v += __shfl_down(v, off);

    __shared__ float wsum[4];
    if ((tid & 63) == 0) wsum[tid >> 6] = v;
    __syncthreads();
    if (tid == 0) out[0] = wsum[0] + wsum[1] + wsum[2] + wsum[3];
}

extern "C" void kernel_launch(void* const* d_in, const int* in_sizes, int n_in,
                              void* d_out, int out_size, void* d_ws, size_t ws_size,
                              hipStream_t stream) {
    const float* feats   = (const float*)d_in[0];
    const float* trans   = (const float*)d_in[1];
    const int*   targets = (const int*)d_in[2];
    const int*   lengths = (const int*)d_in[3];

    float* partialA = (float*)d_ws;        // 256 floats
    float* partialG = partialA + 256;      // 512 floats

    fwd_kernel<<<dim3(BB), dim3(64), 0, stream>>>(feats, trans, targets, lengths, partialA);
    gold_kernel<<<dim3(BB, 2), dim3(256), 0, stream>>>(feats, targets, lengths, partialG);
    final_kernel<<<dim3(1), dim3(256), 0, stream>>>(partialA, partialG, (float*)d_out);
}

// Round 3
// 83.775 us; speedup vs baseline: 2.0869x; 2.0869x over previous
//
#include <hip/hip_runtime.h>
#include <math.h>
#include <stdint.h>

#define BB 256
#define TT 512
#define KK 20
#define START_TAG 18
#define STOP_TAG 19
#define NST 400
#define SEGL 16
#define SEGS 32
#define TASKS (BB*SEGS)      // 8192
#define SEGSTRIDE 420        // floats per segment record (400 M + 20 col-exponents)
#define WS_SEG_OFF 1024      // float offset of segment area in ws

__device__ __forceinline__ float fexp2(float x){ float r; asm("v_exp_f32 %0, %1":"=v"(r):"v"(x)); return r; }
__device__ __forceinline__ float flog2(float x){ float r; asm("v_log_f32 %0, %1":"=v"(r):"v"(x)); return r; }
__device__ __forceinline__ int imax2(int a, int b){ return a > b ? a : b; }

// ================= pass 1: per-segment matrix products =================
// wave = 3 tasks (b,s); lane = (g<3, li<20). Lane loads f-row li of its task,
// exps into LDS; lane also owns COLUMN li of the running product (lane-private
// mat-vec chain, no cross-lane ops). Per-column pow2 renorm every 4 steps.
__global__ __launch_bounds__(64,1) void seg_kernel(
    const float* __restrict__ feats, const int* __restrict__ lengths,
    float* __restrict__ wseg)
{
    constexpr float LOG2E = 1.4426950408889634f;
    const int lane = threadIdx.x;
    int g  = lane / KK;
    int li = lane - KK*g;
    const bool active = (g < 3);
    const int gc = active ? g : 2;
    int task = 3*blockIdx.x + gc;
    const bool realtask = active && (task < TASKS);
    if (task >= TASKS) task = TASKS - 1;
    const int b = task >> 5;
    const int s = task & 31;
    const int seg_start = 1 + SEGL*s;
    const int len = lengths[b];
    int nvalid = len - seg_start;
    nvalid = nvalid < 0 ? 0 : (nvalid > SEGL ? SEGL : nvalid);

    int itmax = nvalid;
    #pragma unroll
    for (int o = 32; o > 0; o >>= 1) itmax = imax2(itmax, __shfl_xor(itmax, o, 64));
    if (itmax == 0) return;

    __shared__ __align__(16) float Ebuf[2][3*404];   // 404-float task stride (bank-spread)

    const float* rp = feats + ((size_t)(b*TT + seg_start))*NST + li*KK;
    int tnext = seg_start;

    float4 fA[5], fB[5];
    float v[KK];
    int cexp = 0;
    #pragma unroll
    for (int k = 0; k < KK; ++k) v[k] = (k == li) ? 1.f : 0.f;

    auto LD = [&](float4 (&d)[5]) {
        const float4* p = (const float4*)rp;
        d[0]=p[0]; d[1]=p[1]; d[2]=p[2]; d[3]=p[3]; d[4]=p[4];
        if (tnext < 511) rp += NST;   // clamp: never read past row 511
        ++tnext;
    };

    auto BODY = [&](float4 (&f)[5], int it) {
        // exp this row into LDS (cooperative E build)
        float* eb = &Ebuf[it & 1][gc*404 + li*KK];
        #pragma unroll
        for (int q = 0; q < 5; ++q) {
            float4 e;
            e.x = fexp2(f[q].x * LOG2E);
            e.y = fexp2(f[q].y * LOG2E);
            e.z = fexp2(f[q].z * LOG2E);
            e.w = fexp2(f[q].w * LOG2E);
            ((float4*)eb)[q] = e;
        }
        LD(f);  // refill this slot (depth-2 pipeline, vmcnt only)
        asm volatile("s_waitcnt lgkmcnt(0)" ::: "memory");  // all lanes' E writes visible
        const float* ebase = &Ebuf[it & 1][gc*404];
        float nv[KK];
        #pragma unroll
        for (int ii = 0; ii < KK; ++ii) {
            const float4* er = (const float4*)(ebase + ii*KK);  // broadcast reads
            float4 e0 = er[0], e1 = er[1], e2 = er[2], e3 = er[3], e4 = er[4];
            float s0 = e0.x * v[0];
            float s1 = e0.y * v[1];
            s0 = fmaf(e0.z, v[2],  s0);  s1 = fmaf(e0.w, v[3],  s1);
            s0 = fmaf(e1.x, v[4],  s0);  s1 = fmaf(e1.y, v[5],  s1);
            s0 = fmaf(e1.z, v[6],  s0);  s1 = fmaf(e1.w, v[7],  s1);
            s0 = fmaf(e2.x, v[8],  s0);  s1 = fmaf(e2.y, v[9],  s1);
            s0 = fmaf(e2.z, v[10], s0);  s1 = fmaf(e2.w, v[11], s1);
            s0 = fmaf(e3.x, v[12], s0);  s1 = fmaf(e3.y, v[13], s1);
            s0 = fmaf(e3.z, v[14], s0);  s1 = fmaf(e3.w, v[15], s1);
            s0 = fmaf(e4.x, v[16], s0);  s1 = fmaf(e4.y, v[17], s1);
            s0 = fmaf(e4.z, v[18], s0);  s1 = fmaf(e4.w, v[19], s1);
            nv[ii] = s0 + s1;
        }
        const bool ok = (it < nvalid);
        #pragma unroll
        for (int k = 0; k < KK; ++k) v[k] = ok ? nv[k] : v[k];
        if ((it & 3) == 3) {             // exact pow2 renorm (neutral for frozen groups)
            float m = v[0];
            #pragma unroll
            for (int k = 1; k < KK; ++k) m = fmaxf(m, v[k]);
            int e = (int)((__float_as_uint(m) >> 23) & 255) - 127;
            float sc = __uint_as_float((unsigned)(127 - e) << 23);
            #pragma unroll
            for (int k = 0; k < KK; ++k) v[k] *= sc;
            cexp += e;
        }
    };

    if (active) { LD(fA); LD(fB); }
    for (int it = 0; it < itmax; ) {
        if (active) BODY(fA, it);
        ++it; if (it >= itmax) break;
        if (active) BODY(fB, it);
        ++it;
    }

    if (realtask && nvalid > 0) {
        float* out = wseg + (size_t)task * SEGSTRIDE;
        #pragma unroll
        for (int ii = 0; ii < KK; ++ii) out[ii*KK + li] = v[ii];  // M[row ii][col li]
        ((int*)out)[NST + li] = cexp;
    }
}

// ================= pass 2: 32 serial segment applications per chain =================
__global__ __launch_bounds__(64,1) void chain_kernel(
    const float* __restrict__ feats, const float* __restrict__ trans,
    const int* __restrict__ targets, const int* __restrict__ lengths,
    const float* __restrict__ wseg, float* __restrict__ partialA)
{
    constexpr float LOG2E = 1.4426950408889634f;
    constexpr float LN2   = 0.6931471805599453f;
    const int b = blockIdx.x;
    const int lane = threadIdx.x;
    const int len = lengths[b];
    const bool act = lane < KK;
    const int li = act ? lane : 0;

    __shared__ __align__(16) int   Ql[KK];
    __shared__ __align__(16) float Ul[KK];

    const float* fb = feats + (size_t)b*TT*NST;
    float a2 = fb[li*KK + START_TAG] * LOG2E;
    float a2m = act ? a2 : -3.0e38f;
    #pragma unroll
    for (int o = 32; o > 0; o >>= 1) a2m = fmaxf(a2m, __shfl_xor(a2m, o, 64));
    float CW = a2m;
    float wk = 0.f;
    if (act) wk = fexp2(a2 - a2m);

    const int nseg = (len - 1 + SEGL - 1) / SEGL;

    if (act && nseg > 0) {
        float4 mA[5], mB[5];
        int cA = 0, cB = 0;
        auto LDM = [&](int s2, float4 (&m)[5], int& c) {
            const float* base = wseg + (size_t)(b*SEGS + s2)*SEGSTRIDE;
            const float4* p = (const float4*)(base + li*KK);
            m[0]=p[0]; m[1]=p[1]; m[2]=p[2]; m[3]=p[3]; m[4]=p[4];
            c = ((const int*)base)[NST + li];
        };
        auto STEP = [&](float4 (&m)[5], int c) {
            int e = (int)((__float_as_uint(wk) >> 23) & 255) - 127;
            Ql[li] = c + e;
            asm volatile("s_waitcnt lgkmcnt(0)" ::: "memory");
            const int4* qp = (const int4*)Ql;
            int4 q0 = qp[0], q1 = qp[1], q2 = qp[2], q3 = qp[3], q4 = qp[4];
            int qmax = imax2(imax2(imax2(q0.x,q0.y),imax2(q0.z,q0.w)),
                       imax2(imax2(imax2(q1.x,q1.y),imax2(q1.z,q1.w)),
                       imax2(imax2(imax2(q2.x,q2.y),imax2(q2.z,q2.w)),
                       imax2(imax2(imax2(q3.x,q3.y),imax2(q3.z,q3.w)),
                             imax2(imax2(q4.x,q4.y),imax2(q4.z,q4.w))))));
            Ul[li] = ldexpf(wk, c - qmax);   // exact pow2 shift (underflow = negligible term)
            asm volatile("s_waitcnt lgkmcnt(0)" ::: "memory");
            const float4* up = (const float4*)Ul;
            float4 u0 = up[0], u1 = up[1], u2 = up[2], u3 = up[3], u4 = up[4];
            float s0 = m[0].x*u0.x, s1 = m[0].y*u0.y;
            s0 = fmaf(m[0].z,u0.z,s0); s1 = fmaf(m[0].w,u0.w,s1);
            s0 = fmaf(m[1].x,u1.x,s0); s1 = fmaf(m[1].y,u1.y,s1);
            s0 = fmaf(m[1].z,u1.z,s0); s1 = fmaf(m[1].w,u1.w,s1);
            s0 = fmaf(m[2].x,u2.x,s0); s1 = fmaf(m[2].y,u2.y,s1);
            s0 = fmaf(m[2].z,u2.z,s0); s1 = fmaf(m[2].w,u2.w,s1);
            s0 = fmaf(m[3].x,u3.x,s0); s1 = fmaf(m[3].y,u3.y,s1);
            s0 = fmaf(m[3].z,u3.z,s0); s1 = fmaf(m[3].w,u3.w,s1);
            s0 = fmaf(m[4].x,u4.x,s0); s1 = fmaf(m[4].y,u4.y,s1);
            s0 = fmaf(m[4].z,u4.z,s0); s1 = fmaf(m[4].w,u4.w,s1);
            wk = s0 + s1;
            CW += (float)qmax;
        };
        LDM(0, mA, cA);
        for (int s2 = 0; s2 < nseg; ) {
            if (s2 + 1 < nseg) LDM(s2 + 1, mB, cB);
            STEP(mA, cA);
            ++s2; if (s2 >= nseg) break;
            if (s2 + 1 < nseg) LDM(s2 + 1, mA, cA);
            STEP(mB, cB);
            ++s2;
        }
    }

    float term = 0.f;
    if (act) term = wk * fexp2(trans[STOP_TAG*KK + li] * LOG2E);
    #pragma unroll
    for (int o = 32; o > 0; o >>= 1) term += __shfl_xor(term, o, 64);
    if (lane == 0) {
        float lse = LN2 * (CW + flog2(term));
        int last = targets[b*TT + len - 1];
        partialA[b] = lse - trans[STOP_TAG*KK + last];
    }
}

// ================= fallback: proven R1 serial forward (used if ws too small) =========
__global__ __launch_bounds__(64,1) void fwd_serial(
    const float* __restrict__ feats, const float* __restrict__ trans,
    const int* __restrict__ targets, const int* __restrict__ lengths,
    float* __restrict__ partialA)
{
    constexpr float LOG2E = 1.4426950408889634f;
    constexpr float LN2   = 0.6931471805599453f;
    const int b    = blockIdx.x;
    const int lane = threadIdx.x;
    const int len  = lengths[b];
    const float* fb = feats + (size_t)b * TT * NST;
    __shared__ __align__(16) float alpha[KK];
    __shared__ __align__(16) float xs[KK];
    const bool act = lane < KK;
    const int  li  = act ? lane : 0;
    if (act) alpha[lane] = fb[lane * KK + START_TAG] * LOG2E;
    __syncthreads();
    float4 b0[5], b1[5], b2[5], b3[5];
    auto LOAD = [&](float4* dst, int t) {
        int tc = (t < len) ? t : (len - 1);
        const float4* p = (const float4*)(fb + (size_t)tc * NST + li * KK);
        dst[0]=p[0]; dst[1]=p[1]; dst[2]=p[2]; dst[3]=p[3]; dst[4]=p[4];
    };
    auto STEP = [&](const float4* bufv) {
        const float4* ap = (const float4*)alpha;
        float a[KK];
        #pragma unroll
        for (int q = 0; q < 5; ++q) {
            float4 av = ap[q];
            a[4*q+0]=av.x; a[4*q+1]=av.y; a[4*q+2]=av.z; a[4*q+3]=av.w;
        }
        float v[KK];
        #pragma unroll
        for (int q = 0; q < 5; ++q) {
            v[4*q+0] = bufv[q].x * LOG2E + a[4*q+0];
            v[4*q+1] = bufv[q].y * LOG2E + a[4*q+1];
            v[4*q+2] = bufv[q].z * LOG2E + a[4*q+2];
            v[4*q+3] = bufv[q].w * LOG2E + a[4*q+3];
        }
        float m = v[0];
        #pragma unroll
        for (int j = 1; j < KK; ++j) m = fmaxf(m, v[j]);
        float s = 0.f;
        #pragma unroll
        for (int j = 0; j < KK; ++j) s += fexp2(v[j] - m);
        float na = m + flog2(s);
        __syncthreads();
        if (act) alpha[lane] = na;
        __syncthreads();
    };
    LOAD(b0,1); LOAD(b1,2); LOAD(b2,3); LOAD(b3,4);
    int t = 1;
    while (t < len) {
        STEP(b0); LOAD(b0, t+4); ++t; if (t >= len) break;
        STEP(b1); LOAD(b1, t+4); ++t; if (t >= len) break;
        STEP(b2); LOAD(b2, t+4); ++t; if (t >= len) break;
        STEP(b3); LOAD(b3, t+4); ++t;
    }
    if (act) xs[lane] = alpha[lane] + trans[STOP_TAG*KK + lane] * LOG2E;
    __syncthreads();
    if (lane == 0) {
        float m = xs[0];
        for (int j = 1; j < KK; ++j) m = fmaxf(m, xs[j]);
        float s = 0.f;
        for (int j = 0; j < KK; ++j) s += fexp2(xs[j] - m);
        float lse = LN2 * (m + flog2(s));
        int last_tag = targets[b*TT + (len-1)];
        partialA[b] = lse - trans[STOP_TAG*KK + last_tag];
    }
}

// ================= gold path + final reduce (unchanged, proven) =================
__global__ __launch_bounds__(256) void gold_kernel(
    const float* __restrict__ feats, const int* __restrict__ targets,
    const int* __restrict__ lengths, float* __restrict__ partialG)
{
    const int b   = blockIdx.x;
    const int tt  = blockIdx.y * 256 + threadIdx.x;
    const int len = lengths[b];
    float val = 0.f;
    if (tt < len) {
        int tgt  = targets[b*TT + tt];
        int prev = (tt > 0) ? targets[b*TT + tt - 1] : START_TAG;
        val = feats[((size_t)b*TT + tt)*NST + tgt*KK + prev];
    }
    #pragma unroll
    for (int off = 32; off > 0; off >>= 1) val += __shfl_down(val, off);
    __shared__ float wsum[4];
    if ((threadIdx.x & 63) == 0) wsum[threadIdx.x >> 6] = val;
    __syncthreads();
    if (threadIdx.x == 0)
        partialG[b*gridDim.y + blockIdx.y] = wsum[0]+wsum[1]+wsum[2]+wsum[3];
}

__global__ __launch_bounds__(256) void final_kernel(
    const float* __restrict__ partialA, const float* __restrict__ partialG,
    float* __restrict__ out)
{
    int tid = threadIdx.x;
    float v = partialA[tid] - partialG[tid] - partialG[tid + 256];
    #pragma unroll
    for (int off = 32; off > 0; off >>= 1) v += __shfl_down(v, off);
    __shared__ float wsum[4];
    if ((tid & 63) == 0) wsum[tid >> 6] = v;
    __syncthreads();
    if (tid == 0) out[0] = wsum[0]+wsum[1]+wsum[2]+wsum[3];
}

extern "C" void kernel_launch(void* const* d_in, const int* in_sizes, int n_in,
                              void* d_out, int out_size, void* d_ws, size_t ws_size,
                              hipStream_t stream) {
    const float* feats   = (const float*)d_in[0];
    const float* trans   = (const float*)d_in[1];
    const int*   targets = (const int*)d_in[2];
    const int*   lengths = (const int*)d_in[3];

    float* ws       = (float*)d_ws;
    float* partialA = ws;          // 256 floats
    float* partialG = ws + 256;    // 512 floats
    float* wseg     = ws + WS_SEG_OFF;
    const size_t need = (size_t)(WS_SEG_OFF + (size_t)TASKS * SEGSTRIDE) * sizeof(float);

    if (ws_size >= need) {
        seg_kernel<<<dim3((TASKS + 2) / 3), dim3(64), 0, stream>>>(feats, lengths, wseg);
        chain_kernel<<<dim3(BB), dim3(64), 0, stream>>>(feats, trans, targets, lengths, wseg, partialA);
    } else {
        fwd_serial<<<dim3(BB), dim3(64), 0, stream>>>(feats, trans, targets, lengths, partialA);
    }
    gold_kernel<<<dim3(BB, 2), dim3(256), 0, stream>>>(feats, targets, lengths, partialG);
    final_kernel<<<dim3(1), dim3(256), 0, stream>>>(partialA, partialG, (float*)d_out);
}